// Round 2
// baseline (1954.327 us; speedup 1.0000x reference)
//
#include <hip/hip_runtime.h>
#include <hip/hip_bf16.h>

// Problem constants (bilinear multi-head self-attention)
#define KH 16    // heads
#define PD 1024  // value-in dim (P == Q)
#define QD 1024  // out dim
#define DD 64    // head dim
#define BB 2     // batch
#define NN 2048  // seq len (M == N)
#define BN 4096  // BB*NN rows

typedef unsigned short u16;  // bf16 raw storage

__device__ __forceinline__ float bf2f(u16 u) {
    return __uint_as_float(((unsigned int)u) << 16);
}
__device__ __forceinline__ u16 f2bf(float f) {
    unsigned int x = __float_as_uint(f);
    x += 0x7FFFu + ((x >> 16) & 1u);  // round-to-nearest-even
    return (u16)(x >> 16);
}

// load 8 bf16 (16B) -> 8 floats
__device__ __forceinline__ void load8f(const u16* p, float* f) {
    uint4 v = *reinterpret_cast<const uint4*>(p);
    u16 t[8];
    *reinterpret_cast<uint4*>(t) = v;
#pragma unroll
    for (int e = 0; e < 8; ++e) f[e] = bf2f(t[e]);
}

// stage 64x64 bf16 tile (global row stride ld) into LDS, LDS row stride 72
__device__ __forceinline__ void stage_tile(const u16* __restrict__ src, int ld,
                                           u16* dst, int tid) {
#pragma unroll
    for (int it = 0; it < 2; ++it) {
        int chunk = tid * 2 + it;    // 512 chunks of 8 bf16
        int row = chunk >> 3;
        int col = (chunk & 7) << 3;
        *reinterpret_cast<uint4*>(dst + row * 72 + col) =
            *reinterpret_cast<const uint4*>(src + row * ld + col);
    }
}

// stage 64x64 tile transposed: dst[col*72+row] = src[row*ld+col]
__device__ __forceinline__ void stage_tile_T(const u16* __restrict__ src, int ld,
                                             u16* dst, int tid) {
#pragma unroll
    for (int it = 0; it < 2; ++it) {
        int chunk = tid * 2 + it;
        int row = chunk >> 3;
        int col = (chunk & 7) << 3;
        uint4 v = *reinterpret_cast<const uint4*>(src + row * ld + col);
        u16 t[8];
        *reinterpret_cast<uint4*>(t) = v;
#pragma unroll
        for (int e = 0; e < 8; ++e) dst[(col + e) * 72 + row] = t[e];
    }
}

// ---------------------------------------------------------------------------
// dtype detector: bf16 N(0,1) data -> ~100% of u16 words have bf16-exponent
// in [96,160); fp32 data -> low halves have uniform exponents (~62% overall).
// flag = 1 (bf16) iff >90% plausible.
// ---------------------------------------------------------------------------
__global__ void detect_kernel(const u16* __restrict__ y, int* flag) {
    __shared__ int cnt;
    if (threadIdx.x == 0) cnt = 0;
    __syncthreads();
    int local = 0;
    for (int i = threadIdx.x; i < 8192; i += 256) {
        u16 u = y[i];
        int e = (u >> 7) & 0xFF;
        if (u == 0 || (e >= 96 && e < 160)) local++;
    }
    atomicAdd(&cnt, local);
    __syncthreads();
    if (threadIdx.x == 0) *flag = (cnt > 7372) ? 1 : 0;
}

// convert src (fp32 or bf16 per *flag) -> canonical bf16. n multiple of 4.
__global__ __launch_bounds__(256) void convert_kernel(
    const void* __restrict__ src, u16* __restrict__ dst, int n,
    const int* __restrict__ flag) {
    int i = (blockIdx.x * 256 + threadIdx.x) * 4;
    if (i >= n) return;
    if (*flag) {
        *reinterpret_cast<uint2*>(dst + i) =
            *reinterpret_cast<const uint2*>((const u16*)src + i);
    } else {
        float4 f = *reinterpret_cast<const float4*>((const float*)src + i);
        u16 t[4] = {f2bf(f.x), f2bf(f.y), f2bf(f.z), f2bf(f.w)};
        *reinterpret_cast<uint2*>(dst + i) = *reinterpret_cast<uint2*>(t);
    }
}

// ---------------------------------------------------------------------------
// Kernel 1: per-head projections.  X/Y/V[k][m][d] = sum_p y'[m][p] * W[k][p][d]
// grid (BN/64, KH, 3), block 256. 64x64 out tile, 4x4 register tile/thread.
// ---------------------------------------------------------------------------
__global__ __launch_bounds__(256) void proj_kernel(
    const u16* __restrict__ yp,                     // [BN][PD] canonical bf16
    const u16* __restrict__ LamX, const u16* __restrict__ LamY,
    const u16* __restrict__ ThX,
    u16* __restrict__ Xk, u16* __restrict__ Yk, u16* __restrict__ Vk) {
    int tid = threadIdx.x;
    int m0 = blockIdx.x * 64;
    int k = blockIdx.y;
    int w = blockIdx.z;
    const u16* W = (w == 0 ? LamX : (w == 1 ? LamY : ThX)) + k * PD * DD;
    u16* out = (w == 0 ? Xk : (w == 1 ? Yk : Vk)) + k * BN * DD;

    __shared__ u16 As[64 * 72];   // As[m][p]
    __shared__ u16 WsT[64 * 72];  // WsT[d][p]
    float acc[4][4] = {};
    int g = tid >> 4, c = tid & 15;

    for (int p0 = 0; p0 < PD; p0 += 64) {
        __syncthreads();
        stage_tile(yp + m0 * PD + p0, PD, As, tid);
        stage_tile_T(W + p0 * DD, DD, WsT, tid);
        __syncthreads();
#pragma unroll
        for (int kk = 0; kk < 64; kk += 8) {
            float a[4][8], b[4][8];
#pragma unroll
            for (int i = 0; i < 4; ++i) load8f(&As[(g + 16 * i) * 72 + kk], a[i]);
#pragma unroll
            for (int j = 0; j < 4; ++j) load8f(&WsT[(c + 16 * j) * 72 + kk], b[j]);
#pragma unroll
            for (int i = 0; i < 4; ++i)
#pragma unroll
                for (int j = 0; j < 4; ++j)
#pragma unroll
                    for (int e = 0; e < 8; ++e) acc[i][j] += a[i][e] * b[j][e];
        }
    }
#pragma unroll
    for (int i = 0; i < 4; ++i)
#pragma unroll
        for (int j = 0; j < 4; ++j)
            out[(m0 + g + 16 * i) * DD + (c + 16 * j)] = f2bf(acc[i][j]);
}

// ---------------------------------------------------------------------------
// Kernel 2: flash attention per (head k, batch b), softmax over keys m.
//   score(m,n) = (X[k][b,m]·Y[k][b,n] + mask[m][n]) / sqrt(D)
//   O[b][n][k][d] = sum_m softmax_m(score) * V[k][b,m][d]
// grid (NN/64 query tiles, KH, BB), block 256.
// ---------------------------------------------------------------------------
__global__ __launch_bounds__(256) void attn_kernel(
    const u16* __restrict__ Xk,    // keys    [KH][BN][DD]
    const u16* __restrict__ Yk,    // queries [KH][BN][DD]
    const u16* __restrict__ Vk,    // values  [KH][BN][DD]
    const u16* __restrict__ mask16,  // [NN][NN] additive, indexed [m][n]
    const float* __restrict__ maskf,
    const int* __restrict__ flag,
    u16* __restrict__ O) {         // [BN][KH*DD]
    int tid = threadIdx.x;
    int q0 = blockIdx.x * 64;
    int k = blockIdx.y;
    int b = blockIdx.z;
    int isbf = *flag;
    const u16* Qp = Yk + (k * BN + b * NN) * DD;
    const u16* Kp = Xk + (k * BN + b * NN) * DD;
    const u16* Vp = Vk + (k * BN + b * NN) * DD;

    __shared__ u16 Qs[64 * 72];
    __shared__ u16 Ks[64 * 72];
    __shared__ float Vs[64 * 68];
    __shared__ float Sld[64 * 65];  // Sld[key][query]
    __shared__ float mst[64], lst[64], alph[64];

    stage_tile(Qp + q0 * DD, DD, Qs, tid);
    if (tid < 64) { mst[tid] = -1e30f; lst[tid] = 0.0f; }

    int g = tid >> 4, c = tid & 15;
    int q_own = tid & 63, dg = tid >> 6;
    float oacc[16] = {};

    for (int m0 = 0; m0 < NN; m0 += 64) {
        __syncthreads();
        stage_tile(Kp + m0 * DD, DD, Ks, tid);
#pragma unroll
        for (int it = 0; it < 2; ++it) {
            int chunk = tid * 2 + it;
            int row = chunk >> 3;
            int col = (chunk & 7) << 3;
            float f[8];
            load8f(Vp + (m0 + row) * DD + col, f);
            *reinterpret_cast<float4*>(&Vs[row * 68 + col]) =
                make_float4(f[0], f[1], f[2], f[3]);
            *reinterpret_cast<float4*>(&Vs[row * 68 + col + 4]) =
                make_float4(f[4], f[5], f[6], f[7]);
        }
        __syncthreads();

        // scores: keys ki=g+16i, queries qj=c+16j
        float s[4][4] = {};
#pragma unroll
        for (int d0 = 0; d0 < 64; d0 += 8) {
            float kf[4][8], qf[4][8];
#pragma unroll
            for (int i = 0; i < 4; ++i) load8f(&Ks[(g + 16 * i) * 72 + d0], kf[i]);
#pragma unroll
            for (int j = 0; j < 4; ++j) load8f(&Qs[(c + 16 * j) * 72 + d0], qf[j]);
#pragma unroll
            for (int i = 0; i < 4; ++i)
#pragma unroll
                for (int j = 0; j < 4; ++j)
#pragma unroll
                    for (int e = 0; e < 8; ++e) s[i][j] += kf[i][e] * qf[j][e];
        }
#pragma unroll
        for (int i = 0; i < 4; ++i)
#pragma unroll
            for (int j = 0; j < 4; ++j) {
                int ki = g + 16 * i, qj = c + 16 * j;
                size_t midx = (size_t)(m0 + ki) * NN + (q0 + qj);
                float mval = isbf ? bf2f(mask16[midx]) : maskf[midx];
                Sld[ki * 65 + qj] = (s[i][j] + mval) * 0.125f;  // 1/sqrt(64)
            }
        __syncthreads();

        // online softmax per query column
        if (tid < 64) {
            int q = tid;
            float mo = mst[q];
            float mx = mo;
            for (int ky = 0; ky < 64; ++ky) mx = fmaxf(mx, Sld[ky * 65 + q]);
            float al = __expf(mo - mx);
            float l = lst[q] * al;
            for (int ky = 0; ky < 64; ++ky) {
                float p = __expf(Sld[ky * 65 + q] - mx);
                Sld[ky * 65 + q] = p;
                l += p;
            }
            mst[q] = mx; lst[q] = l; alph[q] = al;
        }
        __syncthreads();

        float al = alph[q_own];
#pragma unroll
        for (int jj = 0; jj < 16; ++jj) oacc[jj] *= al;
        for (int ky = 0; ky < 64; ++ky) {
            float p = Sld[ky * 65 + q_own];
            const float* vrow = &Vs[ky * 68 + dg * 16];
#pragma unroll
            for (int jj = 0; jj < 16; ++jj) oacc[jj] += p * vrow[jj];
        }
    }

    float inv_l = 1.0f / lst[q_own];
    u16* orow = O + ((size_t)(b * NN + q0 + q_own) * KH + k) * DD + dg * 16;
#pragma unroll
    for (int jj = 0; jj < 16; ++jj) orow[jj] = f2bf(oacc[jj] * inv_l);
}

// ---------------------------------------------------------------------------
// Kernel 3: output projection.  out[m][q] = sum_{k,d} O[m][k*64+d]*ThY[k][q][d]
// grid (BN/64, QD/64), block 256. Stores fp32 or bf16 per *flag.
// ---------------------------------------------------------------------------
__global__ __launch_bounds__(256) void outproj_kernel(
    const u16* __restrict__ O,    // [BN][KH*DD]
    const u16* __restrict__ ThY,  // [KH][QD][DD]
    const int* __restrict__ flag,
    void* __restrict__ outv) {    // [BN][QD] fp32 or bf16
    int tid = threadIdx.x;
    int m0 = blockIdx.x * 64;
    int q0 = blockIdx.y * 64;
    __shared__ u16 As[64 * 72];  // As[m][d]
    __shared__ u16 Ws[64 * 72];  // Ws[q][d]
    float acc[4][4] = {};
    int g = tid >> 4, c = tid & 15;

    for (int k = 0; k < KH; ++k) {
        __syncthreads();
        stage_tile(O + (size_t)m0 * (KH * DD) + k * DD, KH * DD, As, tid);
        stage_tile(ThY + ((size_t)k * QD + q0) * DD, DD, Ws, tid);
        __syncthreads();
#pragma unroll
        for (int kk = 0; kk < 64; kk += 8) {
            float a[4][8], b[4][8];
#pragma unroll
            for (int i = 0; i < 4; ++i) load8f(&As[(g + 16 * i) * 72 + kk], a[i]);
#pragma unroll
            for (int j = 0; j < 4; ++j) load8f(&Ws[(c + 16 * j) * 72 + kk], b[j]);
#pragma unroll
            for (int i = 0; i < 4; ++i)
#pragma unroll
                for (int j = 0; j < 4; ++j)
#pragma unroll
                    for (int e = 0; e < 8; ++e) acc[i][j] += a[i][e] * b[j][e];
        }
    }
    if (*flag) {
        u16* out = (u16*)outv;
#pragma unroll
        for (int i = 0; i < 4; ++i)
#pragma unroll
            for (int j = 0; j < 4; ++j)
                out[(size_t)(m0 + g + 16 * i) * QD + (q0 + c + 16 * j)] =
                    f2bf(acc[i][j]);
    } else {
        float* out = (float*)outv;
#pragma unroll
        for (int i = 0; i < 4; ++i)
#pragma unroll
            for (int j = 0; j < 4; ++j)
                out[(size_t)(m0 + g + 16 * i) * QD + (q0 + c + 16 * j)] = acc[i][j];
    }
}

// ---------------------------------------------------------------------------
extern "C" void kernel_launch(void* const* d_in, const int* in_sizes, int n_in,
                              void* d_out, int out_size, void* d_ws, size_t ws_size,
                              hipStream_t stream) {
    // workspace layout (bytes): [flag 64][ycanon 8.39M][4 weights 2.10M each]
    //                           [Xk][Yk][Vk][Ob] 8.39M each  => ~50.3 MB total
    char* wsb = (char*)d_ws;
    int* flag = (int*)wsb;
    u16* ycan = (u16*)(wsb + 64);
    const size_t NYP = (size_t)BN * PD;         // 4,194,304
    const size_t NW  = (size_t)KH * PD * DD;    // 1,048,576
    u16* LamXc = ycan + NYP;
    u16* LamYc = LamXc + NW;
    u16* ThXc  = LamYc + NW;
    u16* ThYc  = ThXc + NW;
    u16* Xk = ThYc + NW;
    u16* Yk = Xk + (size_t)KH * BN * DD;
    u16* Vk = Yk + (size_t)KH * BN * DD;
    u16* Ob = Vk + (size_t)KH * BN * DD;

    detect_kernel<<<1, 256, 0, stream>>>((const u16*)d_in[0], flag);
    convert_kernel<<<(int)(NYP / 1024), 256, 0, stream>>>(d_in[0], ycan, (int)NYP, flag);
    convert_kernel<<<(int)(NW / 1024), 256, 0, stream>>>(d_in[2], LamXc, (int)NW, flag);
    convert_kernel<<<(int)(NW / 1024), 256, 0, stream>>>(d_in[3], LamYc, (int)NW, flag);
    convert_kernel<<<(int)(NW / 1024), 256, 0, stream>>>(d_in[4], ThXc, (int)NW, flag);
    convert_kernel<<<(int)(NW / 1024), 256, 0, stream>>>(d_in[5], ThYc, (int)NW, flag);

    proj_kernel<<<dim3(BN / 64, KH, 3), 256, 0, stream>>>(ycan, LamXc, LamYc, ThXc,
                                                          Xk, Yk, Vk);
    attn_kernel<<<dim3(NN / 64, KH, BB), 256, 0, stream>>>(
        Xk, Yk, Vk, (const u16*)d_in[1], (const float*)d_in[1], flag, Ob);
    outproj_kernel<<<dim3(BN / 64, QD / 64), 256, 0, stream>>>(Ob, ThYc, flag, d_out);
}

// Round 3
// 353.088 us; speedup vs baseline: 5.5350x; 5.5350x over previous
//
#include <hip/hip_runtime.h>
#include <hip/hip_bf16.h>

// Problem constants (bilinear multi-head self-attention)
#define KH 16    // heads
#define PD 1024  // value-in dim (P == Q)
#define QD 1024  // out dim
#define DD 64    // head dim
#define BB 2     // batch
#define NN 2048  // seq len (M == N)
#define BN 4096  // BB*NN rows

typedef unsigned short u16;  // bf16 raw storage
typedef __attribute__((ext_vector_type(8))) short bf16x8;  // MFMA A/B frag (4 VGPRs)
typedef __attribute__((ext_vector_type(4))) float f32x4;   // MFMA C/D frag

__device__ __forceinline__ float bf2f(u16 u) {
    return __uint_as_float(((unsigned int)u) << 16);
}
__device__ __forceinline__ u16 f2bf(float f) {
    unsigned int x = __float_as_uint(f);
    x += 0x7FFFu + ((x >> 16) & 1u);  // round-to-nearest-even
    return (u16)(x >> 16);
}

__device__ __forceinline__ f32x4 mfma16(bf16x8 a, bf16x8 b, f32x4 c) {
    return __builtin_amdgcn_mfma_f32_16x16x32_bf16(a, b, c, 0, 0, 0);
}

// A/B fragment load from LDS tile with row stride 72 u16 (144B: 16B-aligned,
// breaks power-of-2 bank aliasing -> 2-way max = free).
// frag rows r0..r0+15, k-cols kc..kc+31: lane reads row r0+(lane&15),
// cols kc+(lane>>4)*8 .. +8.
__device__ __forceinline__ bf16x8 ldfrag(const u16* base, int r0, int kc, int lane) {
    return *reinterpret_cast<const bf16x8*>(base + (r0 + (lane & 15)) * 72 + kc +
                                            ((lane >> 4) << 3));
}

// stage ROWS x 64 bf16 tile (global row stride ld) into LDS, stride 72
template <int ROWS>
__device__ __forceinline__ void stage_rows(const u16* __restrict__ src, int ld,
                                           u16* dst, int tid) {
#pragma unroll
    for (int it = 0; it < ROWS / 32; ++it) {
        int chunk = it * 256 + tid;  // chunks of 8 bf16
        int row = chunk >> 3;
        int col = (chunk & 7) << 3;
        *reinterpret_cast<uint4*>(dst + row * 72 + col) =
            *reinterpret_cast<const uint4*>(src + row * ld + col);
    }
}

// stage 64x64 tile transposed: dst[col*72+row] = src[row*ld+col]
__device__ __forceinline__ void stage_tile_T(const u16* __restrict__ src, int ld,
                                             u16* dst, int tid) {
#pragma unroll
    for (int it = 0; it < 2; ++it) {
        int chunk = tid * 2 + it;
        int row = chunk >> 3;
        int col = (chunk & 7) << 3;
        uint4 v = *reinterpret_cast<const uint4*>(src + row * ld + col);
        u16 t[8];
        *reinterpret_cast<uint4*>(t) = v;
#pragma unroll
        for (int e = 0; e < 8; ++e) dst[(col + e) * 72 + row] = t[e];
    }
}

// ---------------------------------------------------------------------------
// dtype detector: bf16 N(0,1) data -> ~100% of u16 words have bf16-exponent
// in [96,160); fp32 low halves are ~uniform. flag=1 (bf16) iff >90% plausible.
// ---------------------------------------------------------------------------
__global__ void detect_kernel(const u16* __restrict__ y, int* flag) {
    __shared__ int cnt;
    if (threadIdx.x == 0) cnt = 0;
    __syncthreads();
    int local = 0;
    for (int i = threadIdx.x; i < 8192; i += 256) {
        u16 u = y[i];
        int e = (u >> 7) & 0xFF;
        if (u == 0 || (e >= 96 && e < 160)) local++;
    }
    atomicAdd(&cnt, local);
    __syncthreads();
    if (threadIdx.x == 0) *flag = (cnt > 7372) ? 1 : 0;
}

// convert src (fp32 or bf16 per *flag) -> canonical bf16. n multiple of 4.
__global__ __launch_bounds__(256) void convert_kernel(
    const void* __restrict__ src, u16* __restrict__ dst, int n,
    const int* __restrict__ flag) {
    int i = (blockIdx.x * 256 + threadIdx.x) * 4;
    if (i >= n) return;
    if (*flag) {
        *reinterpret_cast<uint2*>(dst + i) =
            *reinterpret_cast<const uint2*>((const u16*)src + i);
    } else {
        float4 f = *reinterpret_cast<const float4*>((const float*)src + i);
        u16 t[4] = {f2bf(f.x), f2bf(f.y), f2bf(f.z), f2bf(f.w)};
        *reinterpret_cast<uint2*>(dst + i) = *reinterpret_cast<uint2*>(t);
    }
}

// ---------------------------------------------------------------------------
// mask transpose: maskT[n][m] = mask[m][n] * 0.125 (prescaled, bf16).
// grid (NN/64, NN/64). Runs AFTER proj (buffer aliases ycan).
// ---------------------------------------------------------------------------
__global__ __launch_bounds__(256) void maskT_kernel(const void* __restrict__ msrc,
                                                    u16* __restrict__ maskT,
                                                    const int* __restrict__ flag) {
    __shared__ float T[64][65];
    int tid = threadIdx.x;
    int m0 = blockIdx.x * 64, n0 = blockIdx.y * 64;
    int isbf = *flag;
#pragma unroll
    for (int it = 0; it < 16; ++it) {
        int idx = it * 256 + tid;
        int r = idx >> 6, c = idx & 63;
        size_t g = (size_t)(m0 + r) * NN + n0 + c;
        float v = isbf ? bf2f(((const u16*)msrc)[g]) : ((const float*)msrc)[g];
        T[r][c] = v * 0.125f;
    }
    __syncthreads();
#pragma unroll
    for (int it = 0; it < 16; ++it) {
        int idx = it * 256 + tid;
        int r = idx >> 6, c = idx & 63;
        maskT[(size_t)(n0 + r) * NN + m0 + c] = f2bf(T[c][r]);
    }
}

// ---------------------------------------------------------------------------
// Kernel 1: per-head projections via MFMA.
//   X/Y/V[k][m][d] = sum_p y'[m][p] * W[k][p][d]
// grid (BN/128, KH, 3), block 256 (4 waves). 128m x 64d tile; wave: 32m x 64d.
// ---------------------------------------------------------------------------
__global__ __launch_bounds__(256) void proj_kernel(
    const u16* __restrict__ yp,  // [BN][PD] canonical bf16
    const u16* __restrict__ LamX, const u16* __restrict__ LamY,
    const u16* __restrict__ ThX,
    u16* __restrict__ Xk, u16* __restrict__ Yk, u16* __restrict__ Vk) {
    int tid = threadIdx.x;
    int lane = tid & 63, w = tid >> 6;
    int m0 = blockIdx.x * 128;
    int k = blockIdx.y;
    int sel = blockIdx.z;
    const u16* W = (sel == 0 ? LamX : (sel == 1 ? LamY : ThX)) + k * PD * DD;
    u16* out = (sel == 0 ? Xk : (sel == 1 ? Yk : Vk)) + k * BN * DD;

    __shared__ u16 As[128 * 72];   // As[m][p]
    __shared__ u16 WsT[64 * 72];   // WsT[d][p]
    f32x4 acc[2][4] = {};

    for (int p0 = 0; p0 < PD; p0 += 64) {
        __syncthreads();
        stage_rows<128>(yp + m0 * PD + p0, PD, As, tid);
        stage_tile_T(W + p0 * DD, DD, WsT, tid);
        __syncthreads();
#pragma unroll
        for (int ks = 0; ks < 64; ks += 32) {
            bf16x8 a0 = ldfrag(As, w * 32, ks, lane);
            bf16x8 a1 = ldfrag(As, w * 32 + 16, ks, lane);
#pragma unroll
            for (int j = 0; j < 4; ++j) {
                bf16x8 b = ldfrag(WsT, j * 16, ks, lane);
                acc[0][j] = mfma16(a0, b, acc[0][j]);
                acc[1][j] = mfma16(a1, b, acc[1][j]);
            }
        }
    }
#pragma unroll
    for (int i = 0; i < 2; ++i)
#pragma unroll
        for (int j = 0; j < 4; ++j)
#pragma unroll
            for (int reg = 0; reg < 4; ++reg) {
                int row = m0 + w * 32 + i * 16 + ((lane >> 4) << 2) + reg;
                int col = j * 16 + (lane & 15);
                out[row * DD + col] = f2bf(acc[i][j][reg]);
            }
}

// ---------------------------------------------------------------------------
// Kernel 2: flash attention via MFMA. softmax over keys m.
//   S[q][key] = Q[q].K[key]/8 + mask[key][q]/8 ; O[q][d] = softmax_key(S).V
// grid (NN/64, KH, BB), block 256 (4 waves). wave: 16 q-rows.
// ---------------------------------------------------------------------------
__global__ __launch_bounds__(256) void attn_kernel(
    const u16* __restrict__ Xk,     // keys    [KH][BN][DD]
    const u16* __restrict__ Yk,     // queries [KH][BN][DD]
    const u16* __restrict__ Vk,     // values  [KH][BN][DD]
    const u16* __restrict__ maskT,  // [NN n][NN m] bf16, prescaled by 0.125
    u16* __restrict__ O) {          // [BN][KH*DD]
    int tid = threadIdx.x;
    int lane = tid & 63, w = tid >> 6;
    int q0 = blockIdx.x * 64;
    int k = blockIdx.y;
    int b = blockIdx.z;
    const u16* Qp = Yk + (k * BN + b * NN) * DD;
    const u16* Kp = Xk + (k * BN + b * NN) * DD;
    const u16* Vp = Vk + (k * BN + b * NN) * DD;

    __shared__ u16 Qs[64 * 72];   // Q[q][d]
    __shared__ u16 Ks[64 * 72];   // K[key][d]
    __shared__ u16 Vt[64 * 72];   // V^T[d][key]
    __shared__ u16 Pl[64 * 72];   // P[q][key] bf16 (A-frag layout for PV)
    __shared__ float Sf[64 * 65]; // S[q][key] f32
    __shared__ float mrun[64], lrun[64], alph[64];

    stage_rows<64>(Qp + q0 * DD, DD, Qs, tid);
    if (tid < 64) { mrun[tid] = -1e30f; lrun[tid] = 0.0f; }

    // softmax mapping: 4 adjacent lanes per query -> shuffle combine
    int sq = tid >> 2, squ = tid & 3;
    const u16* mrowbase = maskT + (size_t)(q0 + sq) * NN;

    f32x4 oacc[4] = {};

    for (int m0 = 0; m0 < NN; m0 += 64) {
        __syncthreads();  // prev PV done (and Qs/init visible on iter 0)
        stage_rows<64>(Kp + m0 * DD, DD, Ks, tid);
        stage_tile_T(Vp + m0 * DD, DD, Vt, tid);
        __syncthreads();

        // S = Q K^T : wave w rows q = w*16..+16, cols key 0..64
        f32x4 sacc[4] = {};
#pragma unroll
        for (int ks = 0; ks < 64; ks += 32) {
            bf16x8 a = ldfrag(Qs, w * 16, ks, lane);
#pragma unroll
            for (int j = 0; j < 4; ++j) {
                bf16x8 bK = ldfrag(Ks, j * 16, ks, lane);
                sacc[j] = mfma16(a, bK, sacc[j]);
            }
        }
#pragma unroll
        for (int j = 0; j < 4; ++j)
#pragma unroll
            for (int reg = 0; reg < 4; ++reg)
                Sf[(w * 16 + ((lane >> 4) << 2) + reg) * 65 + j * 16 + (lane & 15)] =
                    sacc[j][reg] * 0.125f;
        __syncthreads();

        // online softmax: thread (sq, squ) handles keys squ*16..+16 of query sq
        float sv[16];
        const u16* mrow = mrowbase + m0 + squ * 16;
        float mx = -1e30f;
#pragma unroll
        for (int j = 0; j < 16; ++j) {
            sv[j] = Sf[sq * 65 + squ * 16 + j] + bf2f(mrow[j]);
            mx = fmaxf(mx, sv[j]);
        }
        mx = fmaxf(mx, __shfl_xor(mx, 1));
        mx = fmaxf(mx, __shfl_xor(mx, 2));
        float mold = mrun[sq];
        float mnew = fmaxf(mold, mx);
        float psum = 0.0f;
        u16 pb[16];
#pragma unroll
        for (int j = 0; j < 16; ++j) {
            float p = __expf(sv[j] - mnew);
            psum += p;
            pb[j] = f2bf(p);
        }
        *reinterpret_cast<uint4*>(Pl + sq * 72 + squ * 16) =
            reinterpret_cast<uint4*>(pb)[0];
        *reinterpret_cast<uint4*>(Pl + sq * 72 + squ * 16 + 8) =
            reinterpret_cast<uint4*>(pb)[1];
        psum += __shfl_xor(psum, 1);
        psum += __shfl_xor(psum, 2);
        __syncthreads();  // Pl complete; mold reads done
        if (squ == 0) {
            float al = __expf(mold - mnew);
            alph[sq] = al;
            mrun[sq] = mnew;
            lrun[sq] = lrun[sq] * al + psum;
        }
        __syncthreads();  // alph visible

        // rescale O accumulator, then O += P V
        float al[4];
#pragma unroll
        for (int reg = 0; reg < 4; ++reg)
            al[reg] = alph[w * 16 + ((lane >> 4) << 2) + reg];
#pragma unroll
        for (int j = 0; j < 4; ++j)
#pragma unroll
            for (int reg = 0; reg < 4; ++reg) oacc[j][reg] *= al[reg];
#pragma unroll
        for (int ks = 0; ks < 64; ks += 32) {
            bf16x8 a = ldfrag(Pl, w * 16, ks, lane);
#pragma unroll
            for (int j = 0; j < 4; ++j) {
                bf16x8 bV = ldfrag(Vt, j * 16, ks, lane);
                oacc[j] = mfma16(a, bV, oacc[j]);
            }
        }
    }

    float li[4];
#pragma unroll
    for (int reg = 0; reg < 4; ++reg)
        li[reg] = 1.0f / lrun[w * 16 + ((lane >> 4) << 2) + reg];
#pragma unroll
    for (int j = 0; j < 4; ++j)
#pragma unroll
        for (int reg = 0; reg < 4; ++reg) {
            int q = w * 16 + ((lane >> 4) << 2) + reg;
            int d = j * 16 + (lane & 15);
            O[((size_t)(b * NN + q0 + q) * KH + k) * DD + d] =
                f2bf(oacc[j][reg] * li[reg]);
        }
}

// ---------------------------------------------------------------------------
// Kernel 3: output projection via MFMA.
//   out[m][q] = sum_{k,d} O[m][k*64+d] * ThY[k][q][d]
// grid (BN/128, QD/64), block 256. 128m x 64q tile; loop over 16 heads.
// ---------------------------------------------------------------------------
__global__ __launch_bounds__(256) void outproj_kernel(
    const u16* __restrict__ O,    // [BN][KH*DD]
    const u16* __restrict__ ThY,  // [KH][QD][DD]
    const int* __restrict__ flag,
    void* __restrict__ outv) {    // [BN][QD] fp32 or bf16
    int tid = threadIdx.x;
    int lane = tid & 63, w = tid >> 6;
    int m0 = blockIdx.x * 128;
    int q0 = blockIdx.y * 64;
    __shared__ u16 As[128 * 72];  // O slice [m][d]
    __shared__ u16 Bs[64 * 72];   // ThY[k] slice [q][d]
    f32x4 acc[2][4] = {};

    for (int k = 0; k < KH; ++k) {
        __syncthreads();
        stage_rows<128>(O + (size_t)m0 * (KH * DD) + k * DD, KH * DD, As, tid);
        stage_rows<64>(ThY + ((size_t)k * QD + q0) * DD, DD, Bs, tid);
        __syncthreads();
#pragma unroll
        for (int ks = 0; ks < 64; ks += 32) {
            bf16x8 a0 = ldfrag(As, w * 32, ks, lane);
            bf16x8 a1 = ldfrag(As, w * 32 + 16, ks, lane);
#pragma unroll
            for (int j = 0; j < 4; ++j) {
                bf16x8 b = ldfrag(Bs, j * 16, ks, lane);
                acc[0][j] = mfma16(a0, b, acc[0][j]);
                acc[1][j] = mfma16(a1, b, acc[1][j]);
            }
        }
    }
    int isbf = *flag;
#pragma unroll
    for (int i = 0; i < 2; ++i)
#pragma unroll
        for (int j = 0; j < 4; ++j)
#pragma unroll
            for (int reg = 0; reg < 4; ++reg) {
                size_t row = m0 + w * 32 + i * 16 + ((lane >> 4) << 2) + reg;
                int col = q0 + j * 16 + (lane & 15);
                if (isbf)
                    ((u16*)outv)[row * QD + col] = f2bf(acc[i][j][reg]);
                else
                    ((float*)outv)[row * QD + col] = acc[i][j][reg];
            }
}

// ---------------------------------------------------------------------------
extern "C" void kernel_launch(void* const* d_in, const int* in_sizes, int n_in,
                              void* d_out, int out_size, void* d_ws, size_t ws_size,
                              hipStream_t stream) {
    // ws layout: [flag 64B][ycan 8.39M (reused as maskT after proj)]
    //            [4 weights 2.10M each][Xk][Yk][Vk][Ob 8.39M each] ~= 50.3 MB
    char* wsb = (char*)d_ws;
    int* flag = (int*)wsb;
    u16* ycan = (u16*)(wsb + 64);
    const size_t NYP = (size_t)BN * PD;       // 4,194,304
    const size_t NW = (size_t)KH * PD * DD;   // 1,048,576
    u16* LamXc = ycan + NYP;
    u16* LamYc = LamXc + NW;
    u16* ThXc = LamYc + NW;
    u16* ThYc = ThXc + NW;
    u16* Xk = ThYc + NW;
    u16* Yk = Xk + (size_t)KH * BN * DD;
    u16* Vk = Yk + (size_t)KH * BN * DD;
    u16* Ob = Vk + (size_t)KH * BN * DD;
    u16* maskT = ycan;  // aliases ycan: written after proj consumes it

    detect_kernel<<<1, 256, 0, stream>>>((const u16*)d_in[0], flag);
    convert_kernel<<<(int)(NYP / 1024), 256, 0, stream>>>(d_in[0], ycan, (int)NYP, flag);
    convert_kernel<<<(int)(NW / 1024), 256, 0, stream>>>(d_in[2], LamXc, (int)NW, flag);
    convert_kernel<<<(int)(NW / 1024), 256, 0, stream>>>(d_in[3], LamYc, (int)NW, flag);
    convert_kernel<<<(int)(NW / 1024), 256, 0, stream>>>(d_in[4], ThXc, (int)NW, flag);
    convert_kernel<<<(int)(NW / 1024), 256, 0, stream>>>(d_in[5], ThYc, (int)NW, flag);

    proj_kernel<<<dim3(BN / 128, KH, 3), 256, 0, stream>>>(ycan, LamXc, LamYc, ThXc,
                                                           Xk, Yk, Vk);
    maskT_kernel<<<dim3(NN / 64, NN / 64), 256, 0, stream>>>(d_in[1], maskT, flag);
    attn_kernel<<<dim3(NN / 64, KH, BB), 256, 0, stream>>>(Xk, Yk, Vk, maskT, Ob);
    outproj_kernel<<<dim3(BN / 128, QD / 64), 256, 0, stream>>>(Ob, ThYc, flag, d_out);
}

// Round 4
// 340.697 us; speedup vs baseline: 5.7363x; 1.0364x over previous
//
#include <hip/hip_runtime.h>
#include <hip/hip_bf16.h>

// Bilinear multi-head self-attention, MI355X
#define KH 16    // heads
#define PD 1024  // value-in dim (P == Q)
#define QD 1024  // out dim
#define DD 64    // head dim
#define BB 2     // batch
#define NN 2048  // seq len
#define BN 4096  // BB*NN rows
#define ST 72    // LDS row stride in u16: 144B rows keep 16B frag alignment,
                 // +4-bank rotation per row (2-way max on frag/vector paths)

typedef unsigned short u16;
typedef __attribute__((ext_vector_type(8))) short bf16x8;  // MFMA A/B frag
typedef __attribute__((ext_vector_type(4))) float f32x4;   // MFMA C/D frag

__device__ __forceinline__ float bf2f(u16 u) {
    return __uint_as_float(((unsigned)u) << 16);
}
__device__ __forceinline__ u16 f2bf(float f) {
    unsigned x = __float_as_uint(f);
    x += 0x7FFFu + ((x >> 16) & 1u);  // RNE
    return (u16)(x >> 16);
}
__device__ __forceinline__ f32x4 mfma16(bf16x8 a, bf16x8 b, f32x4 c) {
    return __builtin_amdgcn_mfma_f32_16x16x32_bf16(a, b, c, 0, 0, 0);
}
// A/B frag: lane reads row r0+(lane&15), k-cols kc+(lane>>4)*8 .. +8 (16B)
__device__ __forceinline__ bf16x8 ldfrag(const u16* base, int r0, int kc, int lane) {
    return *reinterpret_cast<const bf16x8*>(base + (r0 + (lane & 15)) * ST + kc +
                                            ((lane >> 4) << 3));
}
// stage ROWSx64 bf16 tile (row stride ld) into LDS stride ST, vector copies
template <int ROWS>
__device__ __forceinline__ void stage_rows(const u16* __restrict__ src, int ld,
                                           u16* dst, int tid) {
#pragma unroll
    for (int it = 0; it < ROWS / 32; ++it) {
        int chunk = it * 256 + tid;
        int row = chunk >> 3, col = (chunk & 7) << 3;
        *reinterpret_cast<uint4*>(dst + row * ST + col) =
            *reinterpret_cast<const uint4*>(src + row * ld + col);
    }
}

// ---------------------------------------------------------------------------
// dtype detector (+ init mask-nonzero flag to 0)
__global__ void detect_kernel(const u16* __restrict__ y, int* flag, int* mnz) {
    __shared__ int cnt;
    if (threadIdx.x == 0) cnt = 0;
    __syncthreads();
    int local = 0;
    for (int i = threadIdx.x; i < 8192; i += 256) {
        u16 u = y[i];
        int e = (u >> 7) & 0xFF;
        if (u == 0 || (e >= 96 && e < 160)) local++;
    }
    atomicAdd(&cnt, local);
    __syncthreads();
    if (threadIdx.x == 0) {
        *flag = (cnt > 7372) ? 1 : 0;
        *mnz = 0;
    }
}

// mask all-zero check (bitwise OR over raw words)
__global__ __launch_bounds__(256) void mcheck_kernel(const void* __restrict__ msrc,
                                                     const int* __restrict__ flag,
                                                     int* mnz) {
    size_t n4 = (size_t)NN * NN / 8;      // uint4 count if bf16
    if (*flag == 0) n4 *= 2;              // fp32: twice the bytes
    const uint4* p = (const uint4*)msrc;
    unsigned acc = 0;
    for (size_t i = blockIdx.x * 256 + threadIdx.x; i < n4;
         i += (size_t)gridDim.x * 256) {
        uint4 v = p[i];
        acc |= v.x | v.y | v.z | v.w;
    }
    if (acc) atomicOr(mnz, 1);
}

// convert src (fp32 or bf16 per *flag) -> canonical bf16, n multiple of 4
__global__ __launch_bounds__(256) void convert_kernel(
    const void* __restrict__ src, u16* __restrict__ dst, int n,
    const int* __restrict__ flag) {
    int i = (blockIdx.x * 256 + threadIdx.x) * 4;
    if (i >= n) return;
    if (*flag) {
        *reinterpret_cast<uint2*>(dst + i) =
            *reinterpret_cast<const uint2*>((const u16*)src + i);
    } else {
        float4 f = *reinterpret_cast<const float4*>((const float*)src + i);
        u16 t[4] = {f2bf(f.x), f2bf(f.y), f2bf(f.z), f2bf(f.w)};
        *reinterpret_cast<uint2*>(dst + i) = *reinterpret_cast<uint2*>(t);
    }
}

// convert + per-head transpose: [KH][PD][DD] -> [KH][DD][PD] (optional scale)
__global__ __launch_bounds__(256) void convtr_kernel(const void* __restrict__ src,
                                                     u16* __restrict__ dst,
                                                     float scale,
                                                     const int* __restrict__ flag) {
    int k = blockIdx.y, p0 = blockIdx.x * 64;
    int tid = threadIdx.x;
    __shared__ float T[64][65];
    int isbf = *flag;
    const u16* s16 = (const u16*)src + ((size_t)k * PD + p0) * DD;
    const float* s32 = (const float*)src + ((size_t)k * PD + p0) * DD;
#pragma unroll
    for (int it = 0; it < 2; ++it) {
        int chunk = it * 256 + tid;
        int row = chunk >> 3, c8 = (chunk & 7) << 3;
        float f[8];
        if (isbf) {
            uint4 v = *reinterpret_cast<const uint4*>(s16 + row * DD + c8);
            u16 t[8];
            *reinterpret_cast<uint4*>(t) = v;
#pragma unroll
            for (int e = 0; e < 8; ++e) f[e] = bf2f(t[e]);
        } else {
            float4 a = *reinterpret_cast<const float4*>(s32 + row * DD + c8);
            float4 b = *reinterpret_cast<const float4*>(s32 + row * DD + c8 + 4);
            f[0] = a.x; f[1] = a.y; f[2] = a.z; f[3] = a.w;
            f[4] = b.x; f[5] = b.y; f[6] = b.z; f[7] = b.w;
        }
#pragma unroll
        for (int e = 0; e < 8; ++e) T[row][c8 + e] = f[e] * scale;
    }
    __syncthreads();
    u16* drow = dst + (size_t)k * DD * PD + p0;
#pragma unroll
    for (int it = 0; it < 2; ++it) {
        int chunk = it * 256 + tid;
        int d = chunk >> 3, c8 = (chunk & 7) << 3;
        u16 t[8];
#pragma unroll
        for (int e = 0; e < 8; ++e) t[e] = f2bf(T[c8 + e][d]);
        *reinterpret_cast<uint4*>(drow + (size_t)d * PD + c8) =
            *reinterpret_cast<uint4*>(t);
    }
}

// V transpose: [KH][BN][DD] -> [KH][DD][BN]  (bf16 roundtrip exact)
__global__ __launch_bounds__(256) void vtrans_kernel(const u16* __restrict__ Vk,
                                                     u16* __restrict__ Vtg) {
    int k = blockIdx.y, m0 = blockIdx.x * 64;
    int tid = threadIdx.x;
    __shared__ float T[64][65];
    const u16* src = Vk + ((size_t)k * BN + m0) * DD;
#pragma unroll
    for (int it = 0; it < 2; ++it) {
        int chunk = it * 256 + tid;
        int row = chunk >> 3, c8 = (chunk & 7) << 3;
        uint4 v = *reinterpret_cast<const uint4*>(src + row * DD + c8);
        u16 t[8];
        *reinterpret_cast<uint4*>(t) = v;
#pragma unroll
        for (int e = 0; e < 8; ++e) T[row][c8 + e] = bf2f(t[e]);
    }
    __syncthreads();
    u16* dst = Vtg + (size_t)k * DD * BN + m0;
#pragma unroll
    for (int it = 0; it < 2; ++it) {
        int chunk = it * 256 + tid;
        int d = chunk >> 3, c8 = (chunk & 7) << 3;
        u16 t[8];
#pragma unroll
        for (int e = 0; e < 8; ++e) t[e] = f2bf(T[c8 + e][d]);
        *reinterpret_cast<uint4*>(dst + (size_t)d * BN + c8) =
            *reinterpret_cast<uint4*>(t);
    }
}

// mask transpose+prescale (only if mask nonzero): maskT[n][m] = mask[m][n]/8
__global__ __launch_bounds__(256) void maskT_kernel(const void* __restrict__ msrc,
                                                    u16* __restrict__ maskT,
                                                    const int* __restrict__ flag,
                                                    const int* __restrict__ mnz) {
    if (*mnz == 0) return;
    __shared__ float T[64][65];
    int tid = threadIdx.x;
    int m0 = blockIdx.x * 64, n0 = blockIdx.y * 64;
    int isbf = *flag;
#pragma unroll
    for (int it = 0; it < 16; ++it) {
        int idx = it * 256 + tid;
        int r = idx >> 6, c = idx & 63;
        size_t g = (size_t)(m0 + r) * NN + n0 + c;
        float v = isbf ? bf2f(((const u16*)msrc)[g]) : ((const float*)msrc)[g];
        T[r][c] = v * 0.125f;
    }
    __syncthreads();
#pragma unroll
    for (int it = 0; it < 16; ++it) {
        int idx = it * 256 + tid;
        int r = idx >> 6, c = idx & 63;
        maskT[(size_t)(n0 + r) * NN + m0 + c] = f2bf(T[c][r]);
    }
}

// ---------------------------------------------------------------------------
// Kernel 1: projections, 3 weights per block (A staged once).
// grid (BN/128, KH), block 256. Wave: 32m x 64d per weight.
__global__ __launch_bounds__(256, 3) void proj_kernel(
    const u16* __restrict__ yp,     // [BN][PD]
    const u16* __restrict__ LamXt,  // [KH][DD][PD] transposed
    const u16* __restrict__ LamYt,  //   (prescaled 0.125)
    const u16* __restrict__ ThXt,
    u16* __restrict__ Xk, u16* __restrict__ Yk, u16* __restrict__ Vk) {
    int tid = threadIdx.x, lane = tid & 63, w = tid >> 6;
    int m0 = blockIdx.x * 128, k = blockIdx.y;
    __shared__ u16 As[128 * ST];
    __shared__ u16 Ws[3][64 * ST];
    const u16* Wt0 = LamXt + (size_t)k * DD * PD;
    const u16* Wt1 = LamYt + (size_t)k * DD * PD;
    const u16* Wt2 = ThXt + (size_t)k * DD * PD;
    f32x4 acc[3][2][4] = {};

    for (int p0 = 0; p0 < PD; p0 += 64) {
        __syncthreads();
        stage_rows<128>(yp + (size_t)m0 * PD + p0, PD, As, tid);
        stage_rows<64>(Wt0 + p0, PD, Ws[0], tid);
        stage_rows<64>(Wt1 + p0, PD, Ws[1], tid);
        stage_rows<64>(Wt2 + p0, PD, Ws[2], tid);
        __syncthreads();
#pragma unroll
        for (int ks = 0; ks < 64; ks += 32) {
            bf16x8 a0 = ldfrag(As, w * 32, ks, lane);
            bf16x8 a1 = ldfrag(As, w * 32 + 16, ks, lane);
#pragma unroll
            for (int s = 0; s < 3; ++s)
#pragma unroll
                for (int j = 0; j < 4; ++j) {
                    bf16x8 b = ldfrag(Ws[s], j * 16, ks, lane);
                    acc[s][0][j] = mfma16(a0, b, acc[s][0][j]);
                    acc[s][1][j] = mfma16(a1, b, acc[s][1][j]);
                }
        }
    }
    u16* outs[3] = {Xk + (size_t)k * BN * DD, Yk + (size_t)k * BN * DD,
                    Vk + (size_t)k * BN * DD};
    int quad = lane >> 4, col = lane & 15;
#pragma unroll
    for (int s = 0; s < 3; ++s)
#pragma unroll
        for (int i = 0; i < 2; ++i)
#pragma unroll
            for (int j = 0; j < 4; ++j)
#pragma unroll
                for (int reg = 0; reg < 4; ++reg) {
                    int row = m0 + w * 32 + i * 16 + quad * 4 + reg;
                    outs[s][(size_t)row * DD + j * 16 + col] = f2bf(acc[s][i][j][reg]);
                }
}

// ---------------------------------------------------------------------------
// Kernel 2: flash attention. Q in registers, in-register online softmax,
// P through wave-private LDS rows. 2 barriers/tile, 26KB LDS.
// grid (NN/64, KH, BB), block 256 (4 waves, 16 q-rows each).
__global__ __launch_bounds__(256, 4) void attn_kernel(
    const u16* __restrict__ Xk,     // keys    [KH][BN][DD]
    const u16* __restrict__ Yk,     // queries [KH][BN][DD] (prescaled /8)
    const u16* __restrict__ Vtg,    // V^T     [KH][DD][BN]
    const u16* __restrict__ maskT,  // [NN][NN] transposed, prescaled (if mnz)
    const int* __restrict__ mnz,
    u16* __restrict__ O) {          // [BN][KH*DD]
    int tid = threadIdx.x, lane = tid & 63, w = tid >> 6;
    int q0 = blockIdx.x * 64, k = blockIdx.y, b = blockIdx.z;
    const u16* Qp = Yk + ((size_t)k * BN + b * NN + q0) * DD;
    const u16* Kp = Xk + ((size_t)k * BN + b * NN) * DD;
    const u16* Vp = Vtg + (size_t)k * DD * BN + b * NN;
    __shared__ u16 QPl[64 * ST];  // Q staging, then P (wave-private rows)
    __shared__ u16 Ks[64 * ST];
    __shared__ u16 Vt[64 * ST];
    int mz = *mnz;
    int quad = lane >> 4, col = lane & 15;

    stage_rows<64>(Qp, DD, QPl, tid);
    __syncthreads();
    bf16x8 qf0 = ldfrag(QPl, w * 16, 0, lane);
    bf16x8 qf1 = ldfrag(QPl, w * 16, 32, lane);

    float mrun[4], lrun[4];
#pragma unroll
    for (int r = 0; r < 4; ++r) { mrun[r] = -1e30f; lrun[r] = 0.0f; }
    f32x4 oacc[4] = {};

    for (int m0 = 0; m0 < NN; m0 += 64) {
        __syncthreads();  // prev tile's MFMA reads of Ks/Vt done
        stage_rows<64>(Kp + (size_t)m0 * DD, DD, Ks, tid);
        stage_rows<64>(Vp + m0, BN, Vt, tid);
        __syncthreads();

        // S = Q K^T (prescaled): wave rows w*16..+16, keys 0..64
        f32x4 sacc[4] = {};
#pragma unroll
        for (int j = 0; j < 4; ++j)
            sacc[j] = mfma16(qf0, ldfrag(Ks, j * 16, 0, lane), sacc[j]);
#pragma unroll
        for (int j = 0; j < 4; ++j)
            sacc[j] = mfma16(qf1, ldfrag(Ks, j * 16, 32, lane), sacc[j]);

        if (mz) {  // general path only; bench mask == 0 skips
            const u16* mrow =
                maskT + (size_t)(q0 + w * 16 + quad * 4) * NN + m0 + col;
#pragma unroll
            for (int r = 0; r < 4; ++r)
#pragma unroll
                for (int j = 0; j < 4; ++j)
                    sacc[j][r] += bf2f(mrow[(size_t)r * NN + 16 * j]);
        }

        // in-register online softmax: row q = quad*4+r, keys col+16j across
        // the 16 lanes of the quad -> shfl_xor(1,2,4,8) reduction
        float alpha[4];
#pragma unroll
        for (int r = 0; r < 4; ++r) {
            float mx = fmaxf(fmaxf(sacc[0][r], sacc[1][r]),
                             fmaxf(sacc[2][r], sacc[3][r]));
            mx = fmaxf(mx, __shfl_xor(mx, 1));
            mx = fmaxf(mx, __shfl_xor(mx, 2));
            mx = fmaxf(mx, __shfl_xor(mx, 4));
            mx = fmaxf(mx, __shfl_xor(mx, 8));
            float mnew = fmaxf(mrun[r], mx);
            alpha[r] = __expf(mrun[r] - mnew);
            mrun[r] = mnew;
            float ps = 0.0f;
#pragma unroll
            for (int j = 0; j < 4; ++j) {
                float p = __expf(sacc[j][r] - mnew);
                sacc[j][r] = p;
                ps += p;
            }
            ps += __shfl_xor(ps, 1);
            ps += __shfl_xor(ps, 2);
            ps += __shfl_xor(ps, 4);
            ps += __shfl_xor(ps, 8);
            lrun[r] = lrun[r] * alpha[r] + ps;
        }

        // P -> wave-private LDS rows (same-wave write->read: no barrier)
#pragma unroll
        for (int r = 0; r < 4; ++r)
#pragma unroll
            for (int j = 0; j < 4; ++j)
                QPl[(w * 16 + quad * 4 + r) * ST + col + 16 * j] =
                    f2bf(sacc[j][r]);
#pragma unroll
        for (int j = 0; j < 4; ++j)
#pragma unroll
            for (int r = 0; r < 4; ++r) oacc[j][r] *= alpha[r];
        bf16x8 pf0 = ldfrag(QPl, w * 16, 0, lane);
        bf16x8 pf1 = ldfrag(QPl, w * 16, 32, lane);
#pragma unroll
        for (int j = 0; j < 4; ++j)
            oacc[j] = mfma16(pf0, ldfrag(Vt, j * 16, 0, lane), oacc[j]);
#pragma unroll
        for (int j = 0; j < 4; ++j)
            oacc[j] = mfma16(pf1, ldfrag(Vt, j * 16, 32, lane), oacc[j]);
    }

    float li[4];
#pragma unroll
    for (int r = 0; r < 4; ++r) li[r] = 1.0f / lrun[r];
#pragma unroll
    for (int j = 0; j < 4; ++j)
#pragma unroll
        for (int reg = 0; reg < 4; ++reg) {
            int q = q0 + w * 16 + quad * 4 + reg;
            O[((size_t)(b * NN + q) * KH + k) * DD + col + 16 * j] =
                f2bf(oacc[j][reg] * li[reg]);
        }
}

// ---------------------------------------------------------------------------
// Kernel 3: output projection. grid (BN/128, QD/64), block 256.
__global__ __launch_bounds__(256, 4) void outproj_kernel(
    const u16* __restrict__ O,    // [BN][KH*DD]
    const u16* __restrict__ ThY,  // [KH][QD][DD]
    const int* __restrict__ flag,
    void* __restrict__ outv) {    // [BN][QD] fp32 or bf16
    int tid = threadIdx.x, lane = tid & 63, w = tid >> 6;
    int m0 = blockIdx.x * 128, q0 = blockIdx.y * 64;
    __shared__ u16 As[128 * ST];
    __shared__ u16 Bs[64 * ST];
    f32x4 acc[2][4] = {};

    for (int k = 0; k < KH; ++k) {
        __syncthreads();
        stage_rows<128>(O + (size_t)m0 * (KH * DD) + k * DD, KH * DD, As, tid);
        stage_rows<64>(ThY + ((size_t)k * QD + q0) * DD, DD, Bs, tid);
        __syncthreads();
#pragma unroll
        for (int ks = 0; ks < 64; ks += 32) {
            bf16x8 a0 = ldfrag(As, w * 32, ks, lane);
            bf16x8 a1 = ldfrag(As, w * 32 + 16, ks, lane);
#pragma unroll
            for (int j = 0; j < 4; ++j) {
                bf16x8 b = ldfrag(Bs, j * 16, ks, lane);
                acc[0][j] = mfma16(a0, b, acc[0][j]);
                acc[1][j] = mfma16(a1, b, acc[1][j]);
            }
        }
    }
    int isbf = *flag;
    int quad = lane >> 4, col = lane & 15;
#pragma unroll
    for (int i = 0; i < 2; ++i)
#pragma unroll
        for (int j = 0; j < 4; ++j)
#pragma unroll
            for (int reg = 0; reg < 4; ++reg) {
                size_t row = m0 + w * 32 + i * 16 + quad * 4 + reg;
                int c = q0 + j * 16 + col;
                if (isbf)
                    ((u16*)outv)[row * QD + c] = f2bf(acc[i][j][reg]);
                else
                    ((float*)outv)[row * QD + c] = acc[i][j][reg];
            }
}

// ---------------------------------------------------------------------------
extern "C" void kernel_launch(void* const* d_in, const int* in_sizes, int n_in,
                              void* d_out, int out_size, void* d_ws, size_t ws_size,
                              hipStream_t stream) {
    // ws: [flags 64B][ycan 8.39M -> maskT after proj][LamXt|LamYt|ThXt|ThYc
    //     2.1M each][Xk][Yk][Vk(->Ob)][Vtg] 8.39M each  ~= 50.4 MB
    char* wsb = (char*)d_ws;
    int* flag = (int*)wsb;
    int* mnz = (int*)(wsb + 16);
    u16* ycan = (u16*)(wsb + 64);
    const size_t NYP = (size_t)BN * PD;
    const size_t NW = (size_t)KH * PD * DD;
    u16* LamXt = ycan + NYP;
    u16* LamYt = LamXt + NW;
    u16* ThXt = LamYt + NW;
    u16* ThYc = ThXt + NW;
    u16* Xk = ThYc + NW;
    u16* Yk = Xk + (size_t)KH * BN * DD;
    u16* Vk = Yk + (size_t)KH * BN * DD;
    u16* Vtg = Vk + (size_t)KH * BN * DD;
    u16* maskT = ycan;  // aliases ycan (dead after proj)
    u16* Ob = Vk;       // aliases Vk (dead after vtrans)

    detect_kernel<<<1, 256, 0, stream>>>((const u16*)d_in[0], flag, mnz);
    mcheck_kernel<<<256, 256, 0, stream>>>(d_in[1], flag, mnz);
    convert_kernel<<<(int)(NYP / 1024), 256, 0, stream>>>(d_in[0], ycan, (int)NYP, flag);
    convert_kernel<<<(int)(NW / 1024), 256, 0, stream>>>(d_in[5], ThYc, (int)NW, flag);
    convtr_kernel<<<dim3(PD / 64, KH), 256, 0, stream>>>(d_in[2], LamXt, 1.0f, flag);
    convtr_kernel<<<dim3(PD / 64, KH), 256, 0, stream>>>(d_in[3], LamYt, 0.125f, flag);
    convtr_kernel<<<dim3(PD / 64, KH), 256, 0, stream>>>(d_in[4], ThXt, 1.0f, flag);

    proj_kernel<<<dim3(BN / 128, KH), 256, 0, stream>>>(ycan, LamXt, LamYt, ThXt,
                                                        Xk, Yk, Vk);
    vtrans_kernel<<<dim3(BN / 64, KH), 256, 0, stream>>>(Vk, Vtg);
    maskT_kernel<<<dim3(NN / 64, NN / 64), 256, 0, stream>>>(d_in[1], maskT, flag, mnz);
    attn_kernel<<<dim3(NN / 64, KH, BB), 256, 0, stream>>>(Xk, Yk, Vtg, maskT, mnz, Ob);
    outproj_kernel<<<dim3(BN / 128, QD / 64), 256, 0, stream>>>(Ob, ThYc, flag, d_out);
}

// Round 5
// 248.202 us; speedup vs baseline: 7.8740x; 1.3727x over previous
//
#include <hip/hip_runtime.h>
#include <hip/hip_bf16.h>

// Bilinear multi-head self-attention, MI355X
#define KH 16    // heads
#define PD 1024  // value-in dim
#define QD 1024  // out dim
#define DD 64    // head dim
#define BB 2     // batch
#define NN 2048  // seq len
#define BN 4096  // BB*NN rows
#define ST 72    // LDS row stride (u16): 144B rows, 16B-aligned frags, <=2-way banks
#define SOFT_C 12.0f  // fixed softmax offset: exact (cancels); overflow needs s>100

typedef unsigned short u16;
typedef __attribute__((ext_vector_type(8))) short bf16x8;  // K=32 A/B frag
typedef __attribute__((ext_vector_type(4))) short bf16x4;  // K=16 A/B frag
typedef __attribute__((ext_vector_type(4))) float f32x4;   // C/D frag

__device__ __forceinline__ float bf2f(u16 u) {
    return __uint_as_float(((unsigned)u) << 16);
}
__device__ __forceinline__ u16 f2bf(float f) {
    unsigned x = __float_as_uint(f);
    x += 0x7FFFu + ((x >> 16) & 1u);  // RNE
    return (u16)(x >> 16);
}
__device__ __forceinline__ f32x4 mfma_k32(bf16x8 a, bf16x8 b, f32x4 c) {
    return __builtin_amdgcn_mfma_f32_16x16x32_bf16(a, b, c, 0, 0, 0);
}
__device__ __forceinline__ f32x4 mfma_k16(bf16x4 a, bf16x4 b, f32x4 c) {
#if __has_builtin(__builtin_amdgcn_mfma_f32_16x16x16bf16_1k)
    return __builtin_amdgcn_mfma_f32_16x16x16bf16_1k(a, b, c, 0, 0, 0);
#else
    asm("v_mfma_f32_16x16x16_bf16 %0, %1, %2, %0" : "+v"(c) : "v"(a), "v"(b));
    return c;
#endif
}
// K=32 frag: lane -> row r0+(lane&15), k-cols kc+quad*8..+8 (b128)
__device__ __forceinline__ bf16x8 ldfrag(const u16* base, int r0, int kc, int lane) {
    return *reinterpret_cast<const bf16x8*>(base + (r0 + (lane & 15)) * ST + kc +
                                            ((lane >> 4) << 3));
}
// K=16 frag: lane -> row r0+(lane&15), k-cols kc+quad*4..+4 (b64)
__device__ __forceinline__ bf16x4 ldfrag4(const u16* base, int r0, int kc, int lane) {
    return *reinterpret_cast<const bf16x4*>(base + (r0 + (lane & 15)) * ST + kc +
                                            ((lane >> 4) << 2));
}
__device__ __forceinline__ bf16x4 pack4(float a, float b, float c, float d) {
    union { bf16x4 v; __hip_bfloat162 h[2]; } u;
    u.h[0] = __float22bfloat162_rn(make_float2(a, b));
    u.h[1] = __float22bfloat162_rn(make_float2(c, d));
    return u.v;
}
template <int ROWS>
__device__ __forceinline__ void stage_rows(const u16* __restrict__ src, int ld,
                                           u16* dst, int tid) {
#pragma unroll
    for (int it = 0; it < ROWS / 32; ++it) {
        int chunk = it * 256 + tid;
        int row = chunk >> 3, col = (chunk & 7) << 3;
        *reinterpret_cast<uint4*>(dst + row * ST + col) =
            *reinterpret_cast<const uint4*>(src + row * ld + col);
    }
}

// ---------------------------------------------------------------------------
// dtype detector (+ init mask-nonzero flag)
__global__ void detect_kernel(const u16* __restrict__ y, int* flag, int* mnz) {
    __shared__ int cnt;
    if (threadIdx.x == 0) cnt = 0;
    __syncthreads();
    int local = 0;
    for (int i = threadIdx.x; i < 8192; i += 256) {
        u16 u = y[i];
        int e = (u >> 7) & 0xFF;
        if (u == 0 || (e >= 96 && e < 160)) local++;
    }
    atomicAdd(&cnt, local);
    __syncthreads();
    if (threadIdx.x == 0) {
        *flag = (cnt > 7372) ? 1 : 0;
        *mnz = 0;
    }
}

__global__ __launch_bounds__(256) void mcheck_kernel(const void* __restrict__ msrc,
                                                     const int* __restrict__ flag,
                                                     int* mnz) {
    size_t n4 = (size_t)NN * NN / 8;
    if (*flag == 0) n4 *= 2;
    const uint4* p = (const uint4*)msrc;
    unsigned acc = 0;
    for (size_t i = blockIdx.x * 256 + threadIdx.x; i < n4;
         i += (size_t)gridDim.x * 256) {
        uint4 v = p[i];
        acc |= v.x | v.y | v.z | v.w;
    }
    if (acc) atomicOr(mnz, 1);
}

// convert fp32-or-bf16 -> canonical bf16
__global__ __launch_bounds__(256) void convert_kernel(
    const void* __restrict__ src, u16* __restrict__ dst, int n,
    const int* __restrict__ flag) {
    int i = (blockIdx.x * 256 + threadIdx.x) * 4;
    if (i >= n) return;
    if (*flag) {
        *reinterpret_cast<uint2*>(dst + i) =
            *reinterpret_cast<const uint2*>((const u16*)src + i);
    } else {
        float4 f = *reinterpret_cast<const float4*>((const float*)src + i);
        u16 t[4] = {f2bf(f.x), f2bf(f.y), f2bf(f.z), f2bf(f.w)};
        *reinterpret_cast<uint2*>(dst + i) = *reinterpret_cast<uint2*>(t);
    }
}

// mask canonical bf16 prescaled 0.125 (only if nonzero)
__global__ __launch_bounds__(256) void maskc_kernel(const void* __restrict__ src,
                                                    u16* __restrict__ dst,
                                                    const int* __restrict__ flag,
                                                    const int* __restrict__ mnz) {
    if (*mnz == 0) return;
    size_t i = ((size_t)blockIdx.x * 256 + threadIdx.x) * 8;
    float f[8];
    if (*flag) {
        uint4 v = *reinterpret_cast<const uint4*>((const u16*)src + i);
        u16 t[8];
        *reinterpret_cast<uint4*>(t) = v;
#pragma unroll
        for (int e = 0; e < 8; ++e) f[e] = bf2f(t[e]);
    } else {
        float4 a = *reinterpret_cast<const float4*>((const float*)src + i);
        float4 b = *reinterpret_cast<const float4*>((const float*)src + i + 4);
        f[0] = a.x; f[1] = a.y; f[2] = a.z; f[3] = a.w;
        f[4] = b.x; f[5] = b.y; f[6] = b.z; f[7] = b.w;
    }
    u16 t[8];
#pragma unroll
    for (int e = 0; e < 8; ++e) t[e] = f2bf(f[e] * 0.125f);
    *reinterpret_cast<uint4*>(dst + i) = *reinterpret_cast<uint4*>(t);
}

// convert + per-head transpose: [KH][PD][DD] -> [KH][DD][PD] (scale)
__global__ __launch_bounds__(256) void convtr_kernel(const void* __restrict__ src,
                                                     u16* __restrict__ dst,
                                                     float scale,
                                                     const int* __restrict__ flag) {
    int k = blockIdx.y, p0 = blockIdx.x * 64;
    int tid = threadIdx.x;
    __shared__ float T[64][65];
    int isbf = *flag;
    const u16* s16 = (const u16*)src + ((size_t)k * PD + p0) * DD;
    const float* s32 = (const float*)src + ((size_t)k * PD + p0) * DD;
#pragma unroll
    for (int it = 0; it < 2; ++it) {
        int chunk = it * 256 + tid;
        int row = chunk >> 3, c8 = (chunk & 7) << 3;
        float f[8];
        if (isbf) {
            uint4 v = *reinterpret_cast<const uint4*>(s16 + row * DD + c8);
            u16 t[8];
            *reinterpret_cast<uint4*>(t) = v;
#pragma unroll
            for (int e = 0; e < 8; ++e) f[e] = bf2f(t[e]);
        } else {
            float4 a = *reinterpret_cast<const float4*>(s32 + row * DD + c8);
            float4 b = *reinterpret_cast<const float4*>(s32 + row * DD + c8 + 4);
            f[0] = a.x; f[1] = a.y; f[2] = a.z; f[3] = a.w;
            f[4] = b.x; f[5] = b.y; f[6] = b.z; f[7] = b.w;
        }
#pragma unroll
        for (int e = 0; e < 8; ++e) T[row][c8 + e] = f[e] * scale;
    }
    __syncthreads();
    u16* drow = dst + (size_t)k * DD * PD + p0;
#pragma unroll
    for (int it = 0; it < 2; ++it) {
        int chunk = it * 256 + tid;
        int d = chunk >> 3, c8 = (chunk & 7) << 3;
        u16 t[8];
#pragma unroll
        for (int e = 0; e < 8; ++e) t[e] = f2bf(T[c8 + e][d]);
        *reinterpret_cast<uint4*>(drow + (size_t)d * PD + c8) =
            *reinterpret_cast<uint4*>(t);
    }
}

// ThY rearrange: [KH][QD][DD] -> [QD][KH*DD]  (no transpose, convert)
__global__ __launch_bounds__(256) void thyr_kernel(const void* __restrict__ src,
                                                   u16* __restrict__ dst,
                                                   const int* __restrict__ flag) {
    int k = blockIdx.y, q0 = blockIdx.x * 64;
    int tid = threadIdx.x, isbf = *flag;
#pragma unroll
    for (int it = 0; it < 2; ++it) {
        int chunk = it * 256 + tid;
        int row = chunk >> 3, c8 = (chunk & 7) << 3;
        size_t si = ((size_t)k * QD + q0 + row) * DD + c8;
        u16 t[8];
        if (isbf) {
            *reinterpret_cast<uint4*>(t) =
                *reinterpret_cast<const uint4*>((const u16*)src + si);
        } else {
            float4 a = *reinterpret_cast<const float4*>((const float*)src + si);
            float4 b = *reinterpret_cast<const float4*>((const float*)src + si + 4);
            t[0] = f2bf(a.x); t[1] = f2bf(a.y); t[2] = f2bf(a.z); t[3] = f2bf(a.w);
            t[4] = f2bf(b.x); t[5] = f2bf(b.y); t[6] = f2bf(b.z); t[7] = f2bf(b.w);
        }
        *reinterpret_cast<uint4*>(dst + (size_t)(q0 + row) * (KH * DD) + k * DD + c8) =
            *reinterpret_cast<uint4*>(t);
    }
}

// ---------------------------------------------------------------------------
// Kernel 1: projections as one GEMM [BN x PD] x [PD x 3072] over concatenated
// transposed weights (rows n = s*1024 + k*64 + d). V stored transposed.
// grid (BN/128, 3072/128), block 256.
__global__ __launch_bounds__(256, 3) void proj_gemm(
    const u16* __restrict__ A,   // ycan [BN][PD]
    const u16* __restrict__ Bm,  // Wcat [3072][PD]
    u16* __restrict__ Xk, u16* __restrict__ Yk, u16* __restrict__ Vtg) {
    int tid = threadIdx.x, lane = tid & 63, w = tid >> 6;
    int mhalf = w & 1, nhalf = w >> 1;
    int m0 = blockIdx.x * 128, n0 = blockIdx.y * 128;
    __shared__ u16 As[128 * ST];
    __shared__ u16 Bs[128 * ST];
    f32x4 acc[4][4] = {};

    for (int kk = 0; kk < PD; kk += 64) {
        __syncthreads();
        stage_rows<128>(A + (size_t)m0 * PD + kk, PD, As, tid);
        stage_rows<128>(Bm + (size_t)n0 * PD + kk, PD, Bs, tid);
        __syncthreads();
#pragma unroll
        for (int kc = 0; kc < 64; kc += 32) {
            bf16x8 af[4], bf[4];
#pragma unroll
            for (int i = 0; i < 4; ++i) af[i] = ldfrag(As, mhalf * 64 + i * 16, kc, lane);
#pragma unroll
            for (int j = 0; j < 4; ++j) bf[j] = ldfrag(Bs, nhalf * 64 + j * 16, kc, lane);
#pragma unroll
            for (int i = 0; i < 4; ++i)
#pragma unroll
                for (int j = 0; j < 4; ++j) acc[i][j] = mfma_k32(af[i], bf[j], acc[i][j]);
        }
    }
    int nsel = n0 + nhalf * 64;
    int s = nsel >> 10, kh = (nsel >> 6) & 15;
    int quad = lane >> 4, col = lane & 15;
    if (s == 2) {  // V: store transposed [k][d][token], packed b64
        u16* vb = Vtg + (size_t)kh * DD * BN;
#pragma unroll
        for (int i = 0; i < 4; ++i)
#pragma unroll
            for (int j = 0; j < 4; ++j) {
                int d = j * 16 + col;
                int mrow = m0 + mhalf * 64 + i * 16 + quad * 4;
                *reinterpret_cast<bf16x4*>(vb + (size_t)d * BN + mrow) =
                    pack4(acc[i][j][0], acc[i][j][1], acc[i][j][2], acc[i][j][3]);
            }
    } else {  // X/Y row-major [k][token][d]
        u16* ob = (s == 0 ? Xk : Yk) + (size_t)kh * BN * DD;
#pragma unroll
        for (int i = 0; i < 4; ++i)
#pragma unroll
            for (int j = 0; j < 4; ++j)
#pragma unroll
                for (int reg = 0; reg < 4; ++reg) {
                    int mrow = m0 + mhalf * 64 + i * 16 + quad * 4 + reg;
                    ob[(size_t)mrow * DD + j * 16 + col] = f2bf(acc[i][j][reg]);
                }
    }
}

// ---------------------------------------------------------------------------
// Kernel 2: flash attention, S^T form. D-frag of S^T == B-operand of K=16
// MFMA, so P feeds PV straight from registers. Fixed-C softmax (exact).
// grid (NN/128, KH, BB), block 256 (4 waves, 32 q each).
__global__ __launch_bounds__(256, 2) void attn_kernel(
    const u16* __restrict__ Xk,     // keys    [KH][BN][DD]
    const u16* __restrict__ Yk,     // queries [KH][BN][DD] prescaled /8
    const u16* __restrict__ Vtg,    // V^T     [KH][DD][BN]
    const u16* __restrict__ maskc,  // [NN][NN] bf16 prescaled /8 (if mnz)
    const int* __restrict__ mnz,
    u16* __restrict__ O) {          // [BN][KH*DD]
    int tid = threadIdx.x, lane = tid & 63, w = tid >> 6;
    int quad = lane >> 4, col = lane & 15;
    int q0 = blockIdx.x * 128, k = blockIdx.y, b = blockIdx.z;
    const u16* Qp = Yk + ((size_t)k * BN + b * NN + q0) * DD;
    const u16* Kp = Xk + ((size_t)k * BN + b * NN) * DD;
    const u16* Vp = Vtg + (size_t)k * DD * BN + b * NN;
    __shared__ u16 Qs[128 * ST];  // Q staging, then O output staging
    __shared__ u16 Ks[64 * ST];
    __shared__ u16 Vt[64 * ST];
    int mz = *mnz;

    stage_rows<128>(Qp, DD, Qs, tid);
    __syncthreads();
    bf16x8 qf[2][2];  // B-operand: [qgroup][kc]
#pragma unroll
    for (int g = 0; g < 2; ++g)
#pragma unroll
        for (int kc = 0; kc < 2; ++kc)
            qf[g][kc] = ldfrag(Qs, w * 32 + g * 16, kc * 32, lane);

    float lp[2] = {0.0f, 0.0f};
    f32x4 oacc[2][4] = {};  // O^T[d][q]: [qgroup][dgroup]

    for (int m0 = 0; m0 < NN; m0 += 64) {
        __syncthreads();
        stage_rows<64>(Kp + (size_t)m0 * DD, DD, Ks, tid);
        stage_rows<64>(Vp + m0, BN, Vt, tid);
        __syncthreads();

        // S^T[key][q] = K Q^T (prescaled): rows key, cols q (wave's 32 q)
        f32x4 sacc[2][4] = {};  // [qgroup][keygroup]
#pragma unroll
        for (int kg = 0; kg < 4; ++kg) {
            bf16x8 a0 = ldfrag(Ks, kg * 16, 0, lane);
            bf16x8 a1 = ldfrag(Ks, kg * 16, 32, lane);
#pragma unroll
            for (int g = 0; g < 2; ++g) {
                sacc[g][kg] = mfma_k32(a0, qf[g][0], sacc[g][kg]);
                sacc[g][kg] = mfma_k32(a1, qf[g][1], sacc[g][kg]);
            }
        }
        if (mz) {
#pragma unroll
            for (int g = 0; g < 2; ++g)
#pragma unroll
                for (int kg = 0; kg < 4; ++kg)
#pragma unroll
                    for (int reg = 0; reg < 4; ++reg)
                        sacc[g][kg][reg] += bf2f(
                            maskc[(size_t)(m0 + kg * 16 + quad * 4 + reg) * NN +
                                  q0 + w * 32 + g * 16 + col]);
        }
        // exp(s - C), accumulate per-lane partial l, pack P as B-frags
        bf16x4 pb[2][4];
#pragma unroll
        for (int g = 0; g < 2; ++g)
#pragma unroll
            for (int kg = 0; kg < 4; ++kg) {
                float p0 = __expf(sacc[g][kg][0] - SOFT_C);
                float p1 = __expf(sacc[g][kg][1] - SOFT_C);
                float p2 = __expf(sacc[g][kg][2] - SOFT_C);
                float p3 = __expf(sacc[g][kg][3] - SOFT_C);
                lp[g] += (p0 + p1) + (p2 + p3);
                pb[g][kg] = pack4(p0, p1, p2, p3);
            }
        // O^T += V^T P^T  (P from registers; V^T A-frags from LDS)
#pragma unroll
        for (int kg = 0; kg < 4; ++kg)
#pragma unroll
            for (int dg = 0; dg < 4; ++dg) {
                bf16x4 av = ldfrag4(Vt, dg * 16, kg * 16, lane);
#pragma unroll
                for (int g = 0; g < 2; ++g)
                    oacc[g][dg] = mfma_k16(av, pb[g][kg], oacc[g][dg]);
            }
    }

    float inv[2];
#pragma unroll
    for (int g = 0; g < 2; ++g) {
        float l = lp[g];
        l += __shfl_xor(l, 16);
        l += __shfl_xor(l, 32);
        inv[g] = 1.0f / l;
    }
    // O^T frags -> LDS [q_local][d] (packed b64), then coalesced global copy
#pragma unroll
    for (int g = 0; g < 2; ++g)
#pragma unroll
        for (int dg = 0; dg < 4; ++dg)
            *reinterpret_cast<bf16x4*>(Qs + (w * 32 + g * 16 + col) * ST + dg * 16 +
                                       quad * 4) =
                pack4(oacc[g][dg][0] * inv[g], oacc[g][dg][1] * inv[g],
                      oacc[g][dg][2] * inv[g], oacc[g][dg][3] * inv[g]);
    __syncthreads();
    int r = tid >> 1, h = tid & 1;
    const u16* srow = Qs + r * ST + h * 32;
    u16* drow = O + (size_t)(b * NN + q0 + r) * (KH * DD) + k * DD + h * 32;
#pragma unroll
    for (int u = 0; u < 4; ++u)
        *reinterpret_cast<uint4*>(drow + u * 8) =
            *reinterpret_cast<const uint4*>(srow + u * 8);
}

// ---------------------------------------------------------------------------
// Kernel 3: output projection GEMM [BN x 1024] x [1024 x QD].
// grid (BN/128, QD/128), block 256.
__global__ __launch_bounds__(256, 3) void out_gemm(
    const u16* __restrict__ A,   // Ob [BN][KH*DD]
    const u16* __restrict__ Bm,  // ThYr [QD][KH*DD]
    const int* __restrict__ flag,
    void* __restrict__ outv) {
    int tid = threadIdx.x, lane = tid & 63, w = tid >> 6;
    int mhalf = w & 1, nhalf = w >> 1;
    int m0 = blockIdx.x * 128, n0 = blockIdx.y * 128;
    __shared__ u16 As[128 * ST];
    __shared__ u16 Bs[128 * ST];
    f32x4 acc[4][4] = {};

    for (int kk = 0; kk < KH * DD; kk += 64) {
        __syncthreads();
        stage_rows<128>(A + (size_t)m0 * (KH * DD) + kk, KH * DD, As, tid);
        stage_rows<128>(Bm + (size_t)n0 * (KH * DD) + kk, KH * DD, Bs, tid);
        __syncthreads();
#pragma unroll
        for (int kc = 0; kc < 64; kc += 32) {
            bf16x8 af[4], bf[4];
#pragma unroll
            for (int i = 0; i < 4; ++i) af[i] = ldfrag(As, mhalf * 64 + i * 16, kc, lane);
#pragma unroll
            for (int j = 0; j < 4; ++j) bf[j] = ldfrag(Bs, nhalf * 64 + j * 16, kc, lane);
#pragma unroll
            for (int i = 0; i < 4; ++i)
#pragma unroll
                for (int j = 0; j < 4; ++j) acc[i][j] = mfma_k32(af[i], bf[j], acc[i][j]);
        }
    }
    int isbf = *flag;
    int quad = lane >> 4, col = lane & 15;
#pragma unroll
    for (int i = 0; i < 4; ++i)
#pragma unroll
        for (int j = 0; j < 4; ++j)
#pragma unroll
            for (int reg = 0; reg < 4; ++reg) {
                size_t row = m0 + mhalf * 64 + i * 16 + quad * 4 + reg;
                int c = n0 + nhalf * 64 + j * 16 + col;
                if (isbf)
                    ((u16*)outv)[row * QD + c] = f2bf(acc[i][j][reg]);
                else
                    ((float*)outv)[row * QD + c] = acc[i][j][reg];
            }
}

// ---------------------------------------------------------------------------
extern "C" void kernel_launch(void* const* d_in, const int* in_sizes, int n_in,
                              void* d_out, int out_size, void* d_ws, size_t ws_size,
                              hipStream_t stream) {
    // ws: flag|mnz 64B; ycan 8.39M (-> Ob after proj); Wcat 3x2.1M (LamXt,
    // LamYt/8, ThXt contiguous); ThYr 2.1M; Xk 8.39M; Yk 8.39M; Vtg 8.39M;
    // maskc 8.39M  => ~50.3 MB
    char* wsb = (char*)d_ws;
    int* flag = (int*)wsb;
    int* mnz = (int*)(wsb + 16);
    u16* ycan = (u16*)(wsb + 64);
    const size_t NYP = (size_t)BN * PD;
    const size_t NW = (size_t)KH * PD * DD;
    u16* Wcat = ycan + NYP;            // LamXt | LamYt | ThXt
    u16* LamXt = Wcat;
    u16* LamYt = Wcat + NW;
    u16* ThXt = Wcat + 2 * NW;
    u16* ThYr = Wcat + 3 * NW;
    u16* Xk = ThYr + NW;
    u16* Yk = Xk + (size_t)KH * BN * DD;
    u16* Vtg = Yk + (size_t)KH * BN * DD;
    u16* maskc = Vtg + (size_t)KH * BN * DD;
    u16* Ob = ycan;  // aliases ycan (dead after proj_gemm)

    detect_kernel<<<1, 256, 0, stream>>>((const u16*)d_in[0], flag, mnz);
    mcheck_kernel<<<256, 256, 0, stream>>>(d_in[1], flag, mnz);
    convert_kernel<<<(int)(NYP / 1024), 256, 0, stream>>>(d_in[0], ycan, (int)NYP, flag);
    convtr_kernel<<<dim3(PD / 64, KH), 256, 0, stream>>>(d_in[2], LamXt, 1.0f, flag);
    convtr_kernel<<<dim3(PD / 64, KH), 256, 0, stream>>>(d_in[3], LamYt, 0.125f, flag);
    convtr_kernel<<<dim3(PD / 64, KH), 256, 0, stream>>>(d_in[4], ThXt, 1.0f, flag);
    thyr_kernel<<<dim3(QD / 64, KH), 256, 0, stream>>>(d_in[5], ThYr, flag);
    maskc_kernel<<<2048, 256, 0, stream>>>(d_in[1], maskc, flag, mnz);

    proj_gemm<<<dim3(BN / 128, 3072 / 128), 256, 0, stream>>>(ycan, Wcat, Xk, Yk, Vtg);
    attn_kernel<<<dim3(NN / 128, KH, BB), 256, 0, stream>>>(Xk, Yk, Vtg, maskc, mnz, Ob);
    out_gemm<<<dim3(BN / 128, QD / 128), 256, 0, stream>>>(Ob, ThYr, flag, d_out);
}